// Round 5
// baseline (283.353 us; speedup 1.0000x reference)
//
#include <hip/hip_runtime.h>

// Attention B=4,H=16,S=2048,D=64. fp32 in/out, mask int32 (nonzero=masked).
// Round 12: barrier-free, LDS-free main kernel.
//  - K/V fragment blobs (round-11 layout, unchanged) are loaded DIRECTLY to
//    VGPRs: per 32-key tile, 4 K-frag + 4 V-frag global_load_dwordx4, each a
//    contiguous per-lane 16B read. No __shared__, no __syncthreads, no
//    global_load_lds: every wave is an independent MFMA+VALU stream.
//  - K (and mask) prefetched one full tile ahead; V issued at tile start,
//    consumed after QK+SM (~300cyc cover). L2 serves the 16x blob reuse.
//  - waves own 32 q-rows; blocks = 2 waves (128 thr); grid 2048; bijective
//    XCD swizzle keeps each bh's 32 blocks on one XCD.
//  - mask layout back to unpaired Mpt[b][G][q] (simple per-tile stride).
// Blob layout per (bh, g): 8192 shorts (tau = swap23 key order, r7-verified):
//   K frag (sub,dc):    [sub*2048 + dc*512 + lane*8 + j] = K[g*64+sub*32+q32][dc*16+h*8+j]
//   V frag (sub,kk,dh): [4096 + sub*2048 + kk*1024 + dh*512 + lane*8 + j]
//                       = V^T_tau[d=dh*32+q32][u = g*64+sub*32+kk*16+h*8+j]
// MFMA 32x32x16 layouts (verified m74/m101):
//   A: lane holds A[m=lane&31][k=(lane>>5)*8+j]
//   B: lane holds B[k=(lane>>5)*8+j][n=lane&31]
//   C/D: lane holds D[row=(reg&3)+8*(reg>>2)+4*(lane>>5)][col=lane&31]

#define SEQ 2048
#define DIM 64
#define NBH 64
#define LOG2E 1.44269504088896340736f
#define SCL (0.125f * LOG2E)
#define NEG_SCALED -1.25e8f

typedef short bf16x8 __attribute__((ext_vector_type(8)));
typedef float f32x4 __attribute__((ext_vector_type(4)));
typedef float f32x16 __attribute__((ext_vector_type(16)));

static __device__ __forceinline__ unsigned short f2bf(float f) {
    unsigned int u = __float_as_uint(f);
    u += 0x7fffu + ((u >> 16) & 1u);   // RNE
    return (unsigned short)(u >> 16);
}

// ---------------- fused prepass ----------------
// blocks [0,1024): mask; [1024,3072): K-blob; [3072,5120): V-blob
__global__ __launch_bounds__(256)
void prep_all_kernel(const float* __restrict__ K, const float* __restrict__ V,
                     const int* __restrict__ M,
                     unsigned short* __restrict__ Fb, unsigned int* __restrict__ Mpt) {
    const int x = blockIdx.x;
    const int t = threadIdx.x;
    if (x < 1024) {
        // mask: int32 -> 1 bit/key, transposed Mpt[b][G][q], G = 32-key tile.
        __shared__ unsigned int Wt[64][8];
        const int m  = x;                      // 0..1023
        const int b  = m >> 8;
        const int q0 = ((m >> 3) & 31) * 64;
        const int k0 = (m & 7) * 256;
        const int w  = t >> 6, l = t & 63;
        #pragma unroll 4
        for (int row = 0; row < 16; ++row) {
            const int q = q0 + w * 16 + row;
            int4 v4 = *(const int4*)(M + ((size_t)b * SEQ + q) * SEQ + k0 + l * 4);
            unsigned int nib = (unsigned int)(v4.x != 0) | ((unsigned int)(v4.y != 0) << 1)
                             | ((unsigned int)(v4.z != 0) << 2) | ((unsigned int)(v4.w != 0) << 3);
            unsigned int v = nib << (4 * (l & 7));
            v |= __shfl_xor(v, 1);
            v |= __shfl_xor(v, 2);
            v |= __shfl_xor(v, 4);
            if ((l & 7) == 0) Wt[w * 16 + row][l >> 3] = v;
        }
        __syncthreads();
        {
            const int q = t & 63, g0 = t >> 6;
            #pragma unroll
            for (int gg = 0; gg < 2; ++gg) {
                const int g = g0 + gg * 4;
                Mpt[((size_t)b * 64 + (k0 >> 5) + g) * SEQ + q0 + q] = Wt[q][g];
            }
        }
    } else if (x < 3072) {
        // K-blob: one block per (bh, 64-key group); 512 fragment units of 16B.
        const int kb = x - 1024;
        const int bh = kb >> 5;
        const int g  = kb & 31;
        const float* Kg = K + ((size_t)bh * SEQ + g * 64) * DIM;
        unsigned short* Fo = Fb + (((size_t)bh * 32 + g) * 8192);
        #pragma unroll
        for (int i = 0; i < 2; ++i) {
            const int u   = i * 256 + t;          // 0..511
            const int sub = u >> 8;
            const int dc  = (u >> 6) & 3;
            const int ln  = u & 63;
            const int hh  = ln >> 5;
            const int q32 = ln & 31;
            const float* kp = Kg + (size_t)(sub * 32 + q32) * DIM + dc * 16 + hh * 8;
            float4 a = *(const float4*)kp;
            float4 b2 = *(const float4*)(kp + 4);
            union { uint4 q4; unsigned short s[8]; } w;
            w.s[0] = f2bf(a.x); w.s[1] = f2bf(a.y); w.s[2] = f2bf(a.z); w.s[3] = f2bf(a.w);
            w.s[4] = f2bf(b2.x); w.s[5] = f2bf(b2.y); w.s[6] = f2bf(b2.z); w.s[7] = f2bf(b2.w);
            *(uint4*)(Fo + (size_t)u * 8) = w.q4;
        }
    } else {
        // V-blob: one block per (bh, 64-key group). Phase 1: stage 64x64 tile
        // in tau key order (chunk-swizzled for conflict-free phase-2 reads).
        // Phase 2: emit V^T fragments in blob order.
        __shared__ __align__(16) unsigned short T[64 * 64];
        const int vb = x - 3072;
        const int bh = vb >> 5;
        const int g  = vb & 31;
        const int k0 = g * 64;
        {
            const float* Vb = V + ((size_t)bh * SEQ + k0) * DIM;
            #pragma unroll
            for (int j = 0; j < 4; ++j) {
                const int fi = (j * 256 + t) * 4;      // float idx in 64x64 tile
                const int kk = fi >> 6;                // physical key (local)
                const int d0 = fi & 63;                // multiple of 4
                float4 f = *(const float4*)(Vb + fi);
                const int u  = (kk & ~12) | ((kk & 4) << 1) | ((kk & 8) >> 1); // swap23
                const int cs = (d0 >> 4) ^ ((u >> 3) & 3);
                union { uint2 q; unsigned short s[4]; } w4;
                w4.s[0] = f2bf(f.x); w4.s[1] = f2bf(f.y);
                w4.s[2] = f2bf(f.z); w4.s[3] = f2bf(f.w);
                *(uint2*)&T[u * 64 + cs * 16 + (d0 & 15)] = w4.q;
            }
        }
        __syncthreads();
        {
            // thread t: d-pair (2p, 2p+1), unit (sub,kk,hh) = w2
            const int p   = t & 31;
            const int w2  = t >> 5;
            const int sub = w2 >> 2;
            const int kk  = (w2 >> 1) & 1;
            const int hh  = w2 & 1;
            const int dh  = p >> 4;
            const int q32a = (2 * p) & 31;
            const int ub  = sub * 32 + kk * 16 + hh * 8;
            const unsigned int* T32 = (const unsigned int*)T;
            union { uint4 q4; unsigned short s[8]; } o0, o1;
            #pragma unroll
            for (int j = 0; j < 8; ++j) {
                const int u  = ub + j;
                const int ch = (p >> 3) ^ ((u >> 3) & 3);
                unsigned int v = T32[u * 32 + ch * 8 + (p & 7)];
                o0.s[j] = (unsigned short)v;          // d = 2p
                o1.s[j] = (unsigned short)(v >> 16);  // d = 2p+1
            }
            unsigned short* dst = Fb + (((size_t)bh * 32 + g) * 8192) + 4096
                                + sub * 2048 + kk * 1024 + dh * 512 + hh * 256 + q32a * 8;
            *(uint4*)dst       = o0.q4;
            *(uint4*)(dst + 8) = o1.q4;
        }
    }
}

// ---------------- main ----------------

// load 4 fragments (16B/lane each) from a per-lane base (shorts)
#define LDFRAG(fr4, bp)                                                         \
    { fr4[0] = *(const bf16x8*)(bp);                                            \
      fr4[1] = *(const bf16x8*)((bp) + 512);                                    \
      fr4[2] = *(const bf16x8*)((bp) + 1024);                                   \
      fr4[3] = *(const bf16x8*)((bp) + 1536); }

// QK^T (S^T) for one 32-key tile: C-init from mask bits, 4 mfmas over d.
#define TILE_QK_R(sc, kf, mwv)                                                  \
    {                                                                           \
        const unsigned int mq_ = (mwv) >> sh4;                                  \
        _Pragma("unroll")                                                       \
        for (int r = 0; r < 16; ++r) {                                          \
            const int s_ = (r & 3) + 8 * (r >> 2);                              \
            sc[r] = __int_as_float(__builtin_amdgcn_sbfe(mq_, s_, 1) & 0xC2C80000u); \
        }                                                                       \
        __builtin_amdgcn_s_setprio(1);                                          \
        _Pragma("unroll")                                                       \
        for (int dc = 0; dc < 4; ++dc)                                          \
            sc = __builtin_amdgcn_mfma_f32_32x32x16_bf16(kf[dc], qf[dc], sc, 0, 0, 0); \
        __builtin_amdgcn_s_setprio(0);                                          \
    }

// softmax (fixed-max; masked scores init'd to -100) + PV for one tile.
#define TILE_SMPV_R(sc, vf)                                                     \
    {                                                                           \
        float pv_[16];                                                          \
        _Pragma("unroll")                                                       \
        for (int r = 0; r < 16; ++r) pv_[r] = __builtin_amdgcn_exp2f(sc[r]);    \
        _Pragma("unroll")                                                       \
        for (int r = 0; r < 16; r += 4) {                                       \
            ls0 += pv_[r + 0]; ls1 += pv_[r + 1];                               \
            ls2 += pv_[r + 2]; ls3 += pv_[r + 3];                               \
        }                                                                       \
        unsigned int pk_[8];                                                    \
        _Pragma("unroll")                                                       \
        for (int m = 0; m < 8; ++m)                                             \
            asm("v_cvt_pk_bf16_f32 %0, %1, %2"                                  \
                : "=v"(pk_[m]) : "v"(pv_[2 * m]), "v"(pv_[2 * m + 1]));         \
        __builtin_amdgcn_s_setprio(1);                                          \
        _Pragma("unroll")                                                       \
        for (int kk = 0; kk < 2; ++kk) {                                        \
            union { unsigned int u[4]; bf16x8 v; } fr;                          \
            fr.u[0] = pk_[4 * kk + 0]; fr.u[1] = pk_[4 * kk + 1];               \
            fr.u[2] = pk_[4 * kk + 2]; fr.u[3] = pk_[4 * kk + 3];               \
            acc[0] = __builtin_amdgcn_mfma_f32_32x32x16_bf16(vf[kk * 2 + 0], fr.v, acc[0], 0, 0, 0); \
            acc[1] = __builtin_amdgcn_mfma_f32_32x32x16_bf16(vf[kk * 2 + 1], fr.v, acc[1], 0, 0, 0); \
        }                                                                       \
        __builtin_amdgcn_s_setprio(0);                                          \
    }

__global__ __launch_bounds__(128, 3)
void attn_main_kernel(const float* __restrict__ Q,
                      const unsigned short* __restrict__ Fb,
                      const unsigned int* __restrict__ Mpt,
                      float* __restrict__ O)
{
    // XCD swizzle: xcd = n&7 (HW round-robin), each XCD owns 8 consecutive bh
    // (one b); all 32 q-chunk blocks of a bh land on the same XCD -> blob and
    // mask stay L2-resident for the 16x reuse.
    const int n    = blockIdx.x;               // [0,2048)
    const int mI   = n >> 3;                   // [0,256)
    const int bh   = (n & 7) * 8 + (mI >> 5);
    const int qc   = mI & 31;                  // 64-row q-chunk
    const int b    = bh >> 4;
    const int tid  = threadIdx.x;
    const int wave = tid >> 6;
    const int lane = tid & 63;
    const int h    = lane >> 5;                // k-half for 32x32 frags
    const int q32  = lane & 31;
    const int sh4  = 4 * h;
    const int q0   = qc * 64 + wave * 32;      // this wave's 32 q-rows

    // ---- Q B-frags (Q^T): lane holds Q[q=q32][d = dc*16 + h*8 + j], scale folded ----
    bf16x8 qf[4];
    {
        const float* qp = Q + ((size_t)bh * SEQ + q0 + q32) * DIM + h * 8;
        #pragma unroll
        for (int dc = 0; dc < 4; ++dc) {
            float4 xx = *(const float4*)(qp + dc * 16);
            float4 yy = *(const float4*)(qp + dc * 16 + 4);
            qf[dc][0] = (short)f2bf(xx.x * SCL); qf[dc][1] = (short)f2bf(xx.y * SCL);
            qf[dc][2] = (short)f2bf(xx.z * SCL); qf[dc][3] = (short)f2bf(xx.w * SCL);
            qf[dc][4] = (short)f2bf(yy.x * SCL); qf[dc][5] = (short)f2bf(yy.y * SCL);
            qf[dc][6] = (short)f2bf(yy.z * SCL); qf[dc][7] = (short)f2bf(yy.w * SCL);
        }
    }

    // per-lane blob base (this lane's 16B slot within every 1KB fragment unit)
    const unsigned short* pG = Fb + (size_t)bh * 32 * 8192 + lane * 8;
    // mask: Mpt[b][G][q], one dword per lane per 32-key tile
    const unsigned int* mr = Mpt + (size_t)b * 64 * SEQ + (q0 + q32);

    f32x16 acc[2];
    #pragma unroll
    for (int i = 0; i < 16; ++i) { acc[0][i] = 0.f; acc[1][i] = 0.f; }
    float ls0 = 0.f, ls1 = 0.f, ls2 = 0.f, ls3 = 0.f;

    bf16x8 kA[4], kB[4], vC[4];
    unsigned int mA, mB;

    // prologue: K+mask of tile 0
    LDFRAG(kA, pG);
    mA = mr[0];

    #pragma unroll 1
    for (int t = 0; t < 64; t += 2) {
        // prefetch K+mask of odd tile t+1 (same group, +2048)
        LDFRAG(kB, pG + 2048);
        mB = mr[SEQ];
        // V of even tile t: issued now, consumed after QK+SM
        LDFRAG(vC, pG + 4096);
        {
            f32x16 sc;
            TILE_QK_R(sc, kA, mA);
            TILE_SMPV_R(sc, vC);
        }
        pG += 8192;
        mr += 2 * SEQ;
        if (t + 2 < 64) {           // prefetch K+mask of tile t+2 (next group)
            LDFRAG(kA, pG);
            mA = mr[0];
        }
        // V of odd tile t+1 (prev group, +6144)
        LDFRAG(vC, pG - 2048);
        {
            f32x16 sc;
            TILE_QK_R(sc, kB, mB);
            TILE_SMPV_R(sc, vC);
        }
    }

    // ---- epilogue: l(q) = lsum(lane) + lsum(lane^32); store O^T C-layout ----
    float lsum = (ls0 + ls1) + (ls2 + ls3);
    lsum += __shfl_xor(lsum, 32);
    const float inv = 1.f / lsum;
    float* orow = O + ((size_t)bh * SEQ + q0 + q32) * DIM;
    #pragma unroll
    for (int dh = 0; dh < 2; ++dh) {
        #pragma unroll
        for (int r23 = 0; r23 < 4; ++r23) {
            float4 w;
            w.x = acc[dh][4 * r23 + 0] * inv;
            w.y = acc[dh][4 * r23 + 1] * inv;
            w.z = acc[dh][4 * r23 + 2] * inv;
            w.w = acc[dh][4 * r23 + 3] * inv;
            *(float4*)(orow + dh * 32 + r23 * 8 + h * 4) = w;
        }
    }
}

// ---------------- fallback (round-2 kernel, used if ws too small) ----------------
__global__ __launch_bounds__(256)
void attn_fallback_kernel(const float* __restrict__ Q,
                          const float* __restrict__ K,
                          const float* __restrict__ V,
                          const int* __restrict__ mask,
                          float* __restrict__ O)
{
    const int bh   = blockIdx.y;
    const int b    = bh >> 4;
    const int q0   = blockIdx.x * 64;
    const int tid  = threadIdx.x;
    const int wave = tid >> 6;
    const int lane = tid & 63;
    const int quad = lane >> 4;
    const int l16  = lane & 15;

    __shared__ __align__(16) unsigned short Klds[32][72];
    __shared__ __align__(16) unsigned short VT[64][40];
    __shared__ __align__(16) unsigned short Plds[4][16][40];

    const float* Qb = Q + (size_t)bh * SEQ * DIM;
    const float* Kb = K + (size_t)bh * SEQ * DIM;
    const float* Vb = V + (size_t)bh * SEQ * DIM;
    const int*   Mb = mask + (size_t)b * SEQ * SEQ;

    const int qrow_frag = q0 + wave * 16 + l16;
    bf16x8 qf0, qf1;
    {
        const float* qp = Qb + (size_t)qrow_frag * DIM + quad * 8;
        #pragma unroll
        for (int i = 0; i < 8; ++i) {
            qf0[i] = (short)f2bf(qp[i]);
            qf1[i] = (short)f2bf(qp[32 + i]);
        }
    }

    f32x4 acc[4];
    #pragma unroll
    for (int dg = 0; dg < 4; ++dg) acc[dg] = (f32x4){0.f, 0.f, 0.f, 0.f};
    float mrowv[4] = {-INFINITY, -INFINITY, -INFINITY, -INFINITY};
    float lrow[4] = {0.f, 0.f, 0.f, 0.f};

    const int skey = tid >> 3;
    const int sd0  = (tid & 7) * 8;
    const int vkey = tid & 31;
    const int vd0  = (tid >> 5) * 8;
    const int qrow_m = q0 + wave * 16 + quad * 4;

    for (int kb = 0; kb < SEQ; kb += 32) {
        __syncthreads();
        {
            const float* kp = Kb + (size_t)(kb + skey) * DIM + sd0;
            union { uint4 u4; unsigned short s[8]; } kw;
            #pragma unroll
            for (int i = 0; i < 8; ++i) kw.s[i] = f2bf(kp[i]);
            *(uint4*)&Klds[skey][sd0] = kw.u4;
        }
        {
            const float* vp = Vb + (size_t)(kb + vkey) * DIM + vd0;
            #pragma unroll
            for (int i = 0; i < 8; ++i) VT[vd0 + i][vkey] = f2bf(vp[i]);
        }
        __syncthreads();

        f32x4 scr[2];
        scr[0] = (f32x4){0.f, 0.f, 0.f, 0.f};
        scr[1] = (f32x4){0.f, 0.f, 0.f, 0.f};
        #pragma unroll
        for (int nt = 0; nt < 2; ++nt) {
            bf16x8 kf0 = *(const bf16x8*)&Klds[nt * 16 + l16][quad * 8];
            bf16x8 kf1 = *(const bf16x8*)&Klds[nt * 16 + l16][32 + quad * 8];
            scr[nt] = __builtin_amdgcn_mfma_f32_16x16x32_bf16(qf0, kf0, scr[nt], 0, 0, 0);
            scr[nt] = __builtin_amdgcn_mfma_f32_16x16x32_bf16(qf1, kf1, scr[nt], 0, 0, 0);
        }

        float x[2][4];
        #pragma unroll
        for (int nt = 0; nt < 2; ++nt)
            #pragma unroll
            for (int r = 0; r < 4; ++r) {
                int mv = Mb[(size_t)(qrow_m + r) * SEQ + kb + nt * 16 + l16];
                x[nt][r] = mv ? NEG_SCALED : scr[nt][r] * 0.125f;
            }

        float p[2][4];
        #pragma unroll
        for (int r = 0; r < 4; ++r) {
            float rm = fmaxf(x[0][r], x[1][r]);
            #pragma unroll
            for (int off = 1; off < 16; off <<= 1)
                rm = fmaxf(rm, __shfl_xor(rm, off, 16));
            float mn = fmaxf(mrowv[r], rm);
            float alpha = exp2f((mrowv[r] - mn) * LOG2E);
            mrowv[r] = mn;
            float p0 = exp2f((x[0][r] - mn) * LOG2E);
            float p1 = exp2f((x[1][r] - mn) * LOG2E);
            p[0][r] = p0; p[1][r] = p1;
            float rs = p0 + p1;
            #pragma unroll
            for (int off = 1; off < 16; off <<= 1)
                rs += __shfl_xor(rs, off, 16);
            lrow[r] = lrow[r] * alpha + rs;
            #pragma unroll
            for (int dg = 0; dg < 4; ++dg)
                acc[dg][r] *= alpha;
        }

        #pragma unroll
        for (int nt = 0; nt < 2; ++nt)
            #pragma unroll
            for (int r = 0; r < 4; ++r)
                Plds[wave][quad * 4 + r][nt * 16 + l16] = f2bf(p[nt][r]);

        bf16x8 pf = *(const bf16x8*)&Plds[wave][l16][quad * 8];

        #pragma unroll
        for (int dg = 0; dg < 4; ++dg) {
            bf16x8 vf = *(const bf16x8*)&VT[dg * 16 + l16][quad * 8];
            acc[dg] = __builtin_amdgcn_mfma_f32_16x16x32_bf16(pf, vf, acc[dg], 0, 0, 0);
        }
    }

    float* Ob = O + (size_t)bh * SEQ * DIM;
    #pragma unroll
    for (int r = 0; r < 4; ++r) {
        float inv = 1.f / lrow[r];
        #pragma unroll
        for (int dg = 0; dg < 4; ++dg)
            Ob[(size_t)(qrow_m + r) * DIM + dg * 16 + l16] = acc[dg][r] * inv;
    }
}

extern "C" void kernel_launch(void* const* d_in, const int* in_sizes, int n_in,
                              void* d_out, int out_size, void* d_ws, size_t ws_size,
                              hipStream_t stream) {
    const float* Q = (const float*)d_in[0];
    const float* K = (const float*)d_in[1];
    const float* V = (const float*)d_in[2];
    const int* mask = (const int*)d_in[3];
    float*        O = (float*)d_out;

    const size_t szF = (size_t)NBH * 32 * 8192 * 2;        // K+V fragment blobs
    const size_t szM = (size_t)4 * SEQ * (SEQ / 32) * 4;   // packed transposed mask
    const size_t need = szF + szM;

    if (ws_size >= need) {
        unsigned short* Fb = (unsigned short*)d_ws;
        unsigned int*  Mpt = (unsigned int*)((char*)d_ws + szF);

        prep_all_kernel<<<dim3(5120), 256, 0, stream>>>(K, V, mask, Fb, Mpt);
        attn_main_kernel<<<dim3(2048), 128, 0, stream>>>(Q, Fb, Mpt, O);
    } else {
        attn_fallback_kernel<<<dim3(SEQ / 64, NBH), 256, 0, stream>>>(Q, K, V, mask, O);
    }
}

// Round 6
// 276.399 us; speedup vs baseline: 1.0252x; 1.0252x over previous
//
#include <hip/hip_runtime.h>

// Attention B=4,H=16,S=2048,D=64. fp32 in/out, mask int32 (nonzero=masked).
// Round 13: LDS-staged blobs (r11) + 64 q-rows per wave (2 q-halves).
//  - revert r12's direct-to-VGPR (L2-BW bound: per-wave private re-reads).
//  - block = 256 q-rows, 4 waves x 64 rows; grid 512 (8 blocks/bh).
//  - per 32-key subtile: two INDEPENDENT chains (q-half a/b) sharing the
//    same kf/vf LDS reads -> 2x MFMA per LDS byte, 2 ILP chains per wave,
//    half the barriers and half the L2 blob traffic per unit work.
//  - XCD swizzle: xcd=n&7 owns 8 consecutive bh (one batch b).
// Blob layout per (bh, g): 8192 shorts (tau = swap23 key order, r7-verified):
//   K frag (sub,dc):    [sub*2048 + dc*512 + lane*8 + j] = K[g*64+sub*32+q32][dc*16+h*8+j]
//   V frag (sub,kk,dh): [4096 + sub*2048 + kk*1024 + dh*512 + lane*8 + j]
//                       = V^T_tau[d=dh*32+q32][u = g*64+sub*32+kk*16+h*8+j]
// MFMA 32x32x16 layouts (verified m74/m101):
//   A: lane holds A[m=lane&31][k=(lane>>5)*8+j]
//   B: lane holds B[k=(lane>>5)*8+j][n=lane&31]
//   C/D: lane holds D[row=(reg&3)+8*(reg>>2)+4*(lane>>5)][col=lane&31]

#define SEQ 2048
#define DIM 64
#define NBH 64
#define LOG2E 1.44269504088896340736f
#define SCL (0.125f * LOG2E)
#define NEG_SCALED -1.25e8f

typedef short bf16x8 __attribute__((ext_vector_type(8)));
typedef float f32x4 __attribute__((ext_vector_type(4)));
typedef float f32x16 __attribute__((ext_vector_type(16)));

static __device__ __forceinline__ unsigned short f2bf(float f) {
    unsigned int u = __float_as_uint(f);
    u += 0x7fffu + ((u >> 16) & 1u);   // RNE
    return (unsigned short)(u >> 16);
}

// async global->LDS, 16B per lane; LDS dest = wave-uniform base + lane*16
#define GLD16(gp, lp) __builtin_amdgcn_global_load_lds( \
    (const __attribute__((address_space(1))) unsigned int*)(gp), \
    (__attribute__((address_space(3))) unsigned int*)(lp), 16, 0, 0)

// ---------------- fused prepass ----------------
// blocks [0,1024): mask; [1024,3072): K-blob; [3072,5120): V-blob
__global__ __launch_bounds__(256)
void prep_all_kernel(const float* __restrict__ K, const float* __restrict__ V,
                     const int* __restrict__ M,
                     unsigned short* __restrict__ Fb, unsigned int* __restrict__ Mpt) {
    const int x = blockIdx.x;
    const int t = threadIdx.x;
    if (x < 1024) {
        // mask: int32 -> 1 bit/key, transposed Mpt[b][G][q], G = 32-key tile.
        __shared__ unsigned int Wt[64][8];
        const int m  = x;                      // 0..1023
        const int b  = m >> 8;
        const int q0 = ((m >> 3) & 31) * 64;
        const int k0 = (m & 7) * 256;
        const int w  = t >> 6, l = t & 63;
        #pragma unroll 4
        for (int row = 0; row < 16; ++row) {
            const int q = q0 + w * 16 + row;
            int4 v4 = *(const int4*)(M + ((size_t)b * SEQ + q) * SEQ + k0 + l * 4);
            unsigned int nib = (unsigned int)(v4.x != 0) | ((unsigned int)(v4.y != 0) << 1)
                             | ((unsigned int)(v4.z != 0) << 2) | ((unsigned int)(v4.w != 0) << 3);
            unsigned int v = nib << (4 * (l & 7));
            v |= __shfl_xor(v, 1);
            v |= __shfl_xor(v, 2);
            v |= __shfl_xor(v, 4);
            if ((l & 7) == 0) Wt[w * 16 + row][l >> 3] = v;
        }
        __syncthreads();
        {
            const int q = t & 63, g0 = t >> 6;
            #pragma unroll
            for (int gg = 0; gg < 2; ++gg) {
                const int g = g0 + gg * 4;
                Mpt[((size_t)b * 64 + (k0 >> 5) + g) * SEQ + q0 + q] = Wt[q][g];
            }
        }
    } else if (x < 3072) {
        // K-blob: one block per (bh, 64-key group); 512 fragment units of 16B.
        const int kb = x - 1024;
        const int bh = kb >> 5;
        const int g  = kb & 31;
        const float* Kg = K + ((size_t)bh * SEQ + g * 64) * DIM;
        unsigned short* Fo = Fb + (((size_t)bh * 32 + g) * 8192);
        #pragma unroll
        for (int i = 0; i < 2; ++i) {
            const int u   = i * 256 + t;          // 0..511
            const int sub = u >> 8;
            const int dc  = (u >> 6) & 3;
            const int ln  = u & 63;
            const int hh  = ln >> 5;
            const int q32 = ln & 31;
            const float* kp = Kg + (size_t)(sub * 32 + q32) * DIM + dc * 16 + hh * 8;
            float4 a = *(const float4*)kp;
            float4 b2 = *(const float4*)(kp + 4);
            union { uint4 q4; unsigned short s[8]; } w;
            w.s[0] = f2bf(a.x); w.s[1] = f2bf(a.y); w.s[2] = f2bf(a.z); w.s[3] = f2bf(a.w);
            w.s[4] = f2bf(b2.x); w.s[5] = f2bf(b2.y); w.s[6] = f2bf(b2.z); w.s[7] = f2bf(b2.w);
            *(uint4*)(Fo + (size_t)u * 8) = w.q4;
        }
    } else {
        // V-blob: one block per (bh, 64-key group). Phase 1: stage 64x64 tile
        // in tau key order (chunk-swizzled for conflict-free phase-2 reads).
        // Phase 2: emit V^T fragments in blob order.
        __shared__ __align__(16) unsigned short T[64 * 64];
        const int vb = x - 3072;
        const int bh = vb >> 5;
        const int g  = vb & 31;
        const int k0 = g * 64;
        {
            const float* Vb = V + ((size_t)bh * SEQ + k0) * DIM;
            #pragma unroll
            for (int j = 0; j < 4; ++j) {
                const int fi = (j * 256 + t) * 4;      // float idx in 64x64 tile
                const int kk = fi >> 6;                // physical key (local)
                const int d0 = fi & 63;                // multiple of 4
                float4 f = *(const float4*)(Vb + fi);
                const int u  = (kk & ~12) | ((kk & 4) << 1) | ((kk & 8) >> 1); // swap23
                const int cs = (d0 >> 4) ^ ((u >> 3) & 3);
                union { uint2 q; unsigned short s[4]; } w4;
                w4.s[0] = f2bf(f.x); w4.s[1] = f2bf(f.y);
                w4.s[2] = f2bf(f.z); w4.s[3] = f2bf(f.w);
                *(uint2*)&T[u * 64 + cs * 16 + (d0 & 15)] = w4.q;
            }
        }
        __syncthreads();
        {
            // thread t: d-pair (2p, 2p+1), unit (sub,kk,hh) = w2
            const int p   = t & 31;
            const int w2  = t >> 5;
            const int sub = w2 >> 2;
            const int kk  = (w2 >> 1) & 1;
            const int hh  = w2 & 1;
            const int dh  = p >> 4;
            const int q32a = (2 * p) & 31;
            const int ub  = sub * 32 + kk * 16 + hh * 8;
            const unsigned int* T32 = (const unsigned int*)T;
            union { uint4 q4; unsigned short s[8]; } o0, o1;
            #pragma unroll
            for (int j = 0; j < 8; ++j) {
                const int u  = ub + j;
                const int ch = (p >> 3) ^ ((u >> 3) & 3);
                unsigned int v = T32[u * 32 + ch * 8 + (p & 7)];
                o0.s[j] = (unsigned short)v;          // d = 2p
                o1.s[j] = (unsigned short)(v >> 16);  // d = 2p+1
            }
            unsigned short* dst = Fb + (((size_t)bh * 32 + g) * 8192) + 4096
                                + sub * 2048 + kk * 1024 + dh * 512 + hh * 256 + q32a * 8;
            *(uint4*)dst       = o0.q4;
            *(uint4*)(dst + 8) = o1.q4;
        }
    }
}

// ---------------- main ----------------

// QK^T (S^T) for one 32-key subtile, one q-half: C-init from mask bits,
// 4 mfmas over d. kf reads: shared base Bl + imm -> conflict-free.
#define TILE_QK2(sc, qfh, SUBOFF, mwv)                                          \
    {                                                                           \
        const unsigned int mq_ = (mwv) >> sh4;                                  \
        _Pragma("unroll")                                                       \
        for (int r = 0; r < 16; ++r) {                                          \
            const int s_ = (r & 3) + 8 * (r >> 2);                              \
            sc[r] = __int_as_float(__builtin_amdgcn_sbfe(mq_, s_, 1) & 0xC2C80000u); \
        }                                                                       \
        __builtin_amdgcn_s_setprio(1);                                          \
        _Pragma("unroll")                                                       \
        for (int dc = 0; dc < 4; ++dc) {                                        \
            bf16x8 kf = *(const bf16x8*)(Bl + (SUBOFF) + dc * 512);             \
            sc = __builtin_amdgcn_mfma_f32_32x32x16_bf16(kf, qfh[dc], sc, 0, 0, 0); \
        }                                                                       \
        __builtin_amdgcn_s_setprio(0);                                          \
    }

// softmax finish (fixed-max; masked scores init'd to -100): sc -> packed pk,
// lsum chains (4 independent fp32 adds per q-half).
#define TILE_SM2(sc, pk, lsv)                                                   \
    {                                                                           \
        float pv_[16];                                                          \
        _Pragma("unroll")                                                       \
        for (int r = 0; r < 16; ++r) pv_[r] = __builtin_amdgcn_exp2f(sc[r]);    \
        _Pragma("unroll")                                                       \
        for (int r = 0; r < 16; r += 4) {                                       \
            lsv[0] += pv_[r + 0]; lsv[1] += pv_[r + 1];                         \
            lsv[2] += pv_[r + 2]; lsv[3] += pv_[r + 3];                         \
        }                                                                       \
        _Pragma("unroll")                                                       \
        for (int m = 0; m < 8; ++m)                                             \
            asm("v_cvt_pk_bf16_f32 %0, %1, %2"                                  \
                : "=v"(pk[m]) : "v"(pv_[2 * m]), "v"(pv_[2 * m + 1]));          \
    }

// PV for one subtile, BOTH q-halves: each vf LDS read feeds 2 MFMAs.
#define TILE_PV2(pkA, pkB, SUBOFF)                                              \
    {                                                                           \
        __builtin_amdgcn_s_setprio(1);                                          \
        _Pragma("unroll")                                                       \
        for (int kk = 0; kk < 2; ++kk) {                                        \
            union { unsigned int u[4]; bf16x8 v; } fa, fb;                      \
            _Pragma("unroll")                                                   \
            for (int j = 0; j < 4; ++j) { fa.u[j] = pkA[4 * kk + j]; fb.u[j] = pkB[4 * kk + j]; } \
            _Pragma("unroll")                                                   \
            for (int dh = 0; dh < 2; ++dh) {                                    \
                bf16x8 vf = *(const bf16x8*)(Bl + 4096 + (SUBOFF) + kk * 1024 + dh * 512); \
                acc[0][dh] = __builtin_amdgcn_mfma_f32_32x32x16_bf16(vf, fa.v, acc[0][dh], 0, 0, 0); \
                acc[1][dh] = __builtin_amdgcn_mfma_f32_32x32x16_bf16(vf, fb.v, acc[1][dh], 0, 0, 0); \
            }                                                                   \
        }                                                                       \
        __builtin_amdgcn_s_setprio(0);                                          \
    }

__global__ __launch_bounds__(256, 2)
void attn_main_kernel(const float* __restrict__ Q,
                      const unsigned short* __restrict__ Fb,
                      const unsigned int* __restrict__ Mpt,
                      float* __restrict__ O)
{
    // XCD swizzle: xcd = n&7 (HW round-robin); each XCD owns 8 consecutive bh
    // (one batch b). 8 q-blocks per bh, all on the same XCD -> blob+mask
    // L2-resident for the 8x reuse.
    const int n    = blockIdx.x;               // [0,512)
    const int mI   = n >> 3;                   // [0,64)
    const int bh   = (n & 7) * 8 + (mI >> 3);
    const int qb   = mI & 7;                   // 256-row q-block
    const int b    = bh >> 4;
    const int tid  = threadIdx.x;
    const int wave = tid >> 6;
    const int lane = tid & 63;
    const int h    = lane >> 5;                // k-half for 32x32 frags
    const int q32  = lane & 31;
    const int sh4  = 4 * h;
    const int q0   = qb * 256 + wave * 64;     // wave's first q-row (owns 64)

    __shared__ __align__(16) unsigned short Blob[2][8192];   // 16KB per buffer

    // ---- Q B-frags for both q-halves: lane holds Q[q][d=dc*16+h*8+j], scaled ----
    bf16x8 qf[2][4];
    #pragma unroll
    for (int half = 0; half < 2; ++half) {
        const float* qp = Q + ((size_t)bh * SEQ + q0 + half * 32 + q32) * DIM + h * 8;
        #pragma unroll
        for (int dc = 0; dc < 4; ++dc) {
            float4 xx = *(const float4*)(qp + dc * 16);
            float4 yy = *(const float4*)(qp + dc * 16 + 4);
            qf[half][dc][0] = (short)f2bf(xx.x * SCL); qf[half][dc][1] = (short)f2bf(xx.y * SCL);
            qf[half][dc][2] = (short)f2bf(xx.z * SCL); qf[half][dc][3] = (short)f2bf(xx.w * SCL);
            qf[half][dc][4] = (short)f2bf(yy.x * SCL); qf[half][dc][5] = (short)f2bf(yy.y * SCL);
            qf[half][dc][6] = (short)f2bf(yy.z * SCL); qf[half][dc][7] = (short)f2bf(yy.w * SCL);
        }
    }

    // ---- staging: linear copy, blob layout == LDS layout ----
    const unsigned short* fg = Fb + (size_t)bh * 32 * 8192 + wave * 2048 + lane * 8;

    // mask: Mpt[b][G][q]; one dword per lane per subtile per q-half
    const unsigned int* mpA = Mpt + (size_t)b * 64 * SEQ + (q0 + q32);
    const unsigned int* mpB = mpA + 32;

    f32x16 acc[2][2];
    #pragma unroll
    for (int i = 0; i < 16; ++i) {
        acc[0][0][i] = 0.f; acc[0][1][i] = 0.f;
        acc[1][0][i] = 0.f; acc[1][1][i] = 0.f;
    }
    float lsA[4] = {0.f, 0.f, 0.f, 0.f};
    float lsB[4] = {0.f, 0.f, 0.f, 0.f};

    // prologue: stage group 0 + mask words
    #pragma unroll
    for (int c = 0; c < 4; ++c)
        GLD16(fg + c * 512, &Blob[0][wave * 2048 + c * 512]);
    unsigned int mwA0 = mpA[0],   mwA1 = mpA[SEQ];
    unsigned int mwB0 = mpB[0],   mwB1 = mpB[SEQ];

    #pragma unroll 1
    for (int g = 0; g < SEQ / 64; ++g) {
        __syncthreads();   // drains vmcnt -> buf (g&1) ready for all waves;
                           // prefetch below is 1 group old at next drain

        unsigned int nA0 = 0, nA1 = 0, nB0 = 0, nB1 = 0;
        if (g + 1 < SEQ / 64) {
            const unsigned short* fgn = fg + (size_t)(g + 1) * 8192;
            const int nb = (g + 1) & 1;
            #pragma unroll
            for (int c = 0; c < 4; ++c)
                GLD16(fgn + c * 512, &Blob[nb][wave * 2048 + c * 512]);
            nA0 = mpA[(2 * g + 2) * SEQ]; nA1 = mpA[(2 * g + 3) * SEQ];
            nB0 = mpB[(2 * g + 2) * SEQ]; nB1 = mpB[(2 * g + 3) * SEQ];
        }

        const unsigned short* Bl = &Blob[g & 1][0] + lane * 8;

        // subtile 0: two independent chains (q-half a, b) share kf/vf reads
        {
            f32x16 scA, scB;
            TILE_QK2(scA, qf[0], 0, mwA0);
            TILE_QK2(scB, qf[1], 0, mwB0);
            unsigned int pkA[8], pkB[8];
            TILE_SM2(scA, pkA, lsA);
            TILE_SM2(scB, pkB, lsB);
            TILE_PV2(pkA, pkB, 0);
        }
        // subtile 1
        {
            f32x16 scA, scB;
            TILE_QK2(scA, qf[0], 2048, mwA1);
            TILE_QK2(scB, qf[1], 2048, mwB1);
            unsigned int pkA[8], pkB[8];
            TILE_SM2(scA, pkA, lsA);
            TILE_SM2(scB, pkB, lsB);
            TILE_PV2(pkA, pkB, 2048);
        }

        mwA0 = nA0; mwA1 = nA1; mwB0 = nB0; mwB1 = nB1;
    }

    // ---- epilogue: l(q) = lsum(lane) + lsum(lane^32); store O^T C-layout ----
    #pragma unroll
    for (int half = 0; half < 2; ++half) {
        float lsum = half == 0 ? (lsA[0] + lsA[1]) + (lsA[2] + lsA[3])
                               : (lsB[0] + lsB[1]) + (lsB[2] + lsB[3]);
        lsum += __shfl_xor(lsum, 32);
        const float inv = 1.f / lsum;
        float* orow = O + ((size_t)bh * SEQ + q0 + half * 32 + q32) * DIM;
        #pragma unroll
        for (int dh = 0; dh < 2; ++dh) {
            #pragma unroll
            for (int r23 = 0; r23 < 4; ++r23) {
                float4 w;
                w.x = acc[half][dh][4 * r23 + 0] * inv;
                w.y = acc[half][dh][4 * r23 + 1] * inv;
                w.z = acc[half][dh][4 * r23 + 2] * inv;
                w.w = acc[half][dh][4 * r23 + 3] * inv;
                *(float4*)(orow + dh * 32 + r23 * 8 + h * 4) = w;
            }
        }
    }
}

// ---------------- fallback (round-2 kernel, used if ws too small) ----------------
__global__ __launch_bounds__(256)
void attn_fallback_kernel(const float* __restrict__ Q,
                          const float* __restrict__ K,
                          const float* __restrict__ V,
                          const int* __restrict__ mask,
                          float* __restrict__ O)
{
    const int bh   = blockIdx.y;
    const int b    = bh >> 4;
    const int q0   = blockIdx.x * 64;
    const int tid  = threadIdx.x;
    const int wave = tid >> 6;
    const int lane = tid & 63;
    const int quad = lane >> 4;
    const int l16  = lane & 15;

    __shared__ __align__(16) unsigned short Klds[32][72];
    __shared__ __align__(16) unsigned short VT[64][40];
    __shared__ __align__(16) unsigned short Plds[4][16][40];

    const float* Qb = Q + (size_t)bh * SEQ * DIM;
    const float* Kb = K + (size_t)bh * SEQ * DIM;
    const float* Vb = V + (size_t)bh * SEQ * DIM;
    const int*   Mb = mask + (size_t)b * SEQ * SEQ;

    const int qrow_frag = q0 + wave * 16 + l16;
    bf16x8 qf0, qf1;
    {
        const float* qp = Qb + (size_t)qrow_frag * DIM + quad * 8;
        #pragma unroll
        for (int i = 0; i < 8; ++i) {
            qf0[i] = (short)f2bf(qp[i]);
            qf1[i] = (short)f2bf(qp[32 + i]);
        }
    }

    f32x4 acc[4];
    #pragma unroll
    for (int dg = 0; dg < 4; ++dg) acc[dg] = (f32x4){0.f, 0.f, 0.f, 0.f};
    float mrowv[4] = {-INFINITY, -INFINITY, -INFINITY, -INFINITY};
    float lrow[4] = {0.f, 0.f, 0.f, 0.f};

    const int skey = tid >> 3;
    const int sd0  = (tid & 7) * 8;
    const int vkey = tid & 31;
    const int vd0  = (tid >> 5) * 8;
    const int qrow_m = q0 + wave * 16 + quad * 4;

    for (int kb = 0; kb < SEQ; kb += 32) {
        __syncthreads();
        {
            const float* kp = Kb + (size_t)(kb + skey) * DIM + sd0;
            union { uint4 u4; unsigned short s[8]; } kw;
            #pragma unroll
            for (int i = 0; i < 8; ++i) kw.s[i] = f2bf(kp[i]);
            *(uint4*)&Klds[skey][sd0] = kw.u4;
        }
        {
            const float* vp = Vb + (size_t)(kb + vkey) * DIM + vd0;
            #pragma unroll
            for (int i = 0; i < 8; ++i) VT[vd0 + i][vkey] = f2bf(vp[i]);
        }
        __syncthreads();

        f32x4 scr[2];
        scr[0] = (f32x4){0.f, 0.f, 0.f, 0.f};
        scr[1] = (f32x4){0.f, 0.f, 0.f, 0.f};
        #pragma unroll
        for (int nt = 0; nt < 2; ++nt) {
            bf16x8 kf0 = *(const bf16x8*)&Klds[nt * 16 + l16][quad * 8];
            bf16x8 kf1 = *(const bf16x8*)&Klds[nt * 16 + l16][32 + quad * 8];
            scr[nt] = __builtin_amdgcn_mfma_f32_16x16x32_bf16(qf0, kf0, scr[nt], 0, 0, 0);
            scr[nt] = __builtin_amdgcn_mfma_f32_16x16x32_bf16(qf1, kf1, scr[nt], 0, 0, 0);
        }

        float x[2][4];
        #pragma unroll
        for (int nt = 0; nt < 2; ++nt)
            #pragma unroll
            for (int r = 0; r < 4; ++r) {
                int mv = Mb[(size_t)(qrow_m + r) * SEQ + kb + nt * 16 + l16];
                x[nt][r] = mv ? NEG_SCALED : scr[nt][r] * 0.125f;
            }

        float p[2][4];
        #pragma unroll
        for (int r = 0; r < 4; ++r) {
            float rm = fmaxf(x[0][r], x[1][r]);
            #pragma unroll
            for (int off = 1; off < 16; off <<= 1)
                rm = fmaxf(rm, __shfl_xor(rm, off, 16));
            float mn = fmaxf(mrowv[r], rm);
            float alpha = exp2f((mrowv[r] - mn) * LOG2E);
            mrowv[r] = mn;
            float p0 = exp2f((x[0][r] - mn) * LOG2E);
            float p1 = exp2f((x[1][r] - mn) * LOG2E);
            p[0][r] = p0; p[1][r] = p1;
            float rs = p0 + p1;
            #pragma unroll
            for (int off = 1; off < 16; off <<= 1)
                rs += __shfl_xor(rs, off, 16);
            lrow[r] = lrow[r] * alpha + rs;
            #pragma unroll
            for (int dg = 0; dg < 4; ++dg)
                acc[dg][r] *= alpha;
        }

        #pragma unroll
        for (int nt = 0; nt < 2; ++nt)
            #pragma unroll
            for (int r = 0; r < 4; ++r)
                Plds[wave][quad * 4 + r][nt * 16 + l16] = f2bf(p[nt][r]);

        bf16x8 pf = *(const bf16x8*)&Plds[wave][l16][quad * 8];

        #pragma unroll
        for (int dg = 0; dg < 4; ++dg) {
            bf16x8 vf = *(const bf16x8*)&VT[dg * 16 + l16][quad * 8];
            acc[dg] = __builtin_amdgcn_mfma_f32_16x16x32_bf16(pf, vf, acc[dg], 0, 0, 0);
        }
    }

    float* Ob = O + (size_t)bh * SEQ * DIM;
    #pragma unroll
    for (int r = 0; r < 4; ++r) {
        float inv = 1.f / lrow[r];
        #pragma unroll
        for (int dg = 0; dg < 4; ++dg)
            Ob[(size_t)(qrow_m + r) * DIM + dg * 16 + l16] = acc[dg][r] * inv;
    }
}

extern "C" void kernel_launch(void* const* d_in, const int* in_sizes, int n_in,
                              void* d_out, int out_size, void* d_ws, size_t ws_size,
                              hipStream_t stream) {
    const float* Q = (const float*)d_in[0];
    const float* K = (const float*)d_in[1];
    const float* V = (const float*)d_in[2];
    const int* mask = (const int*)d_in[3];
    float*        O = (float*)d_out;

    const size_t szF = (size_t)NBH * 32 * 8192 * 2;        // K+V fragment blobs
    const size_t szM = (size_t)4 * SEQ * (SEQ / 32) * 4;   // packed transposed mask
    const size_t need = szF + szM;

    if (ws_size >= need) {
        unsigned short* Fb = (unsigned short*)d_ws;
        unsigned int*  Mpt = (unsigned int*)((char*)d_ws + szF);

        prep_all_kernel<<<dim3(5120), 256, 0, stream>>>(K, V, mask, Fb, Mpt);
        attn_main_kernel<<<dim3(512), 256, 0, stream>>>(Q, Fb, Mpt, O);
    } else {
        attn_fallback_kernel<<<dim3(SEQ / 64, NBH), 256, 0, stream>>>(Q, K, V, mask, O);
    }
}